// Round 1
// baseline (34.096 us; speedup 1.0000x reference)
//
#include <hip/hip_runtime.h>
#include <stdint.h>

typedef short bf16x8 __attribute__((ext_vector_type(8)));
typedef float f32x4 __attribute__((ext_vector_type(4)));
typedef unsigned short u16x8 __attribute__((ext_vector_type(8)));

#define B_DIM 512
#define IN_DIM 1024
#define OUT_DIM 1024
#define KPACK 4096   // 4 bf16 per original int16 k-element

static __device__ __forceinline__ unsigned short bfbits(float f) {
    // exact values only (ints <= 2^23 scaled by powers of two) -> low mantissa bits are zero
    return (unsigned short)(__builtin_bit_cast(unsigned int, f) >> 16);
}

static __device__ __forceinline__ void quant_split(float v, int& hi, int& lo) {
    float t = rintf(v * 4096.0f);                 // round half-to-even, matches jnp.round
    t = fminf(fmaxf(t, -32768.0f), 32767.0f);
    int q = (int)t;
    lo = ((q + 128) & 255) - 128;                  // centered low byte in [-128,127]
    hi = (q - lo) >> 8;                            // in [-128,128], exact in bf16
}

// Pack A'' = [512][4096]: (xhi, xlo, xhi, xlo) per k
// Pack W'' = [1024][4096]: (whi*65536, whi*256, wlo*256, wlo) per k
// => sum_j A''[b][j]*W''[o][j] = sum_k xq[b,k]*wq[o,k] exactly (up to f32 accum)
__global__ __launch_bounds__(256) void prep_kernel(const float* __restrict__ x,
                                                   const float* __restrict__ w,
                                                   unsigned short* __restrict__ Ap,
                                                   unsigned short* __restrict__ Wp) {
    const int XQ = (B_DIM * IN_DIM) / 4;    // 131072 quads
    const int WQ = (OUT_DIM * IN_DIM) / 4;  // 262144 quads
    int gid = blockIdx.x * 256 + threadIdx.x;
    bool isx = gid < XQ;
    int g = isx ? gid : gid - XQ;
    if (!isx && g >= WQ) return;

    const float* src = isx ? x : w;
    f32x4 v = ((const f32x4*)src)[g];

    unsigned short o[16];
#pragma unroll
    for (int j = 0; j < 4; ++j) {
        int hi, lo;
        quant_split(v[j], hi, lo);
        if (isx) {
            unsigned short h = bfbits((float)hi);
            unsigned short l = bfbits((float)lo);
            o[4 * j + 0] = h; o[4 * j + 1] = l;
            o[4 * j + 2] = h; o[4 * j + 3] = l;
        } else {
            o[4 * j + 0] = bfbits((float)(hi * 65536));
            o[4 * j + 1] = bfbits((float)(hi * 256));
            o[4 * j + 2] = bfbits((float)(lo * 256));
            o[4 * j + 3] = bfbits((float)lo);
        }
    }
    unsigned short* dst = (isx ? Ap : Wp) + (size_t)g * 16;
    ((u16x8*)dst)[0] = *(const u16x8*)&o[0];
    ((u16x8*)dst)[1] = *(const u16x8*)&o[8];
}

// NT bf16 GEMM: C[512,1024] = A''[512,4096] * W''[1024,4096]^T, f32 acc.
// 64x64 tile, BK=128, 4 waves of 32x32, K-split 2 -> 256 blocks.
// LDS layout XOR-swizzled in 16B columns: phys_c16 = logical_c16 ^ (row&7),
// applied on the pre-swizzled global source (global_load_lds dest stays linear)
// and on the ds_read address (rule: both-sides-or-neither).
__global__ __launch_bounds__(256) void gemm_kernel(const unsigned short* __restrict__ Ap,
                                                   const unsigned short* __restrict__ Wp,
                                                   float* __restrict__ Cp) {
    __shared__ unsigned short sA[64 * 128];
    __shared__ unsigned short sB[64 * 128];

    int bid = blockIdx.x;
    bid = (bid & 7) * 32 + (bid >> 3);   // XCD swizzle (bijective, 256 % 8 == 0)
    int mblk = bid & 7;
    int nblk = (bid >> 3) & 15;
    int ks = bid >> 7;

    int t = threadIdx.x;
    int lane = t & 63;
    int wv = t >> 6;
    int wm = wv >> 1, wn = wv & 1;

    int m0 = mblk * 64, n0 = nblk * 64;
    int kbase = ks * 2048;

    f32x4 acc[2][2] = {};

    for (int it = 0; it < 16; ++it) {
        int kk0 = kbase + it * 128;
#pragma unroll
        for (int i = 0; i < 4; ++i) {
            int idx = i * 256 + t;          // linear LDS 16B slot
            int row = idx >> 4;
            int c = idx & 15;
            int csw = c ^ (row & 7);        // fetch the element that belongs in this slot
            const unsigned short* ga = Ap + (size_t)(m0 + row) * KPACK + kk0 + csw * 8;
            __builtin_amdgcn_global_load_lds(
                (const __attribute__((address_space(1))) void*)ga,
                (__attribute__((address_space(3))) void*)&sA[idx * 8], 16, 0, 0);
            const unsigned short* gb = Wp + (size_t)(n0 + row) * KPACK + kk0 + csw * 8;
            __builtin_amdgcn_global_load_lds(
                (const __attribute__((address_space(1))) void*)gb,
                (__attribute__((address_space(3))) void*)&sB[idx * 8], 16, 0, 0);
        }
        __syncthreads();

#pragma unroll
        for (int kk = 0; kk < 4; ++kk) {
            bf16x8 af[2], bfr[2];
#pragma unroll
            for (int m = 0; m < 2; ++m) {
                int row = wm * 32 + m * 16 + (lane & 15);
                int slot = (kk * 4 + (lane >> 4)) ^ (row & 7);
                af[m] = *(const bf16x8*)&sA[row * 128 + slot * 8];
            }
#pragma unroll
            for (int n = 0; n < 2; ++n) {
                int row = wn * 32 + n * 16 + (lane & 15);
                int slot = (kk * 4 + (lane >> 4)) ^ (row & 7);
                bfr[n] = *(const bf16x8*)&sB[row * 128 + slot * 8];
            }
#pragma unroll
            for (int m = 0; m < 2; ++m)
#pragma unroll
                for (int n = 0; n < 2; ++n)
                    acc[m][n] = __builtin_amdgcn_mfma_f32_16x16x32_bf16(
                        af[m], bfr[n], acc[m][n], 0, 0, 0);
        }
        __syncthreads();
    }

    // C/D layout (verified m89): col = lane&15, row = (lane>>4)*4 + reg
    float* cbase = Cp + (size_t)ks * (B_DIM * OUT_DIM);
#pragma unroll
    for (int m = 0; m < 2; ++m) {
        int grow0 = m0 + wm * 32 + m * 16 + ((lane >> 4) << 2);
#pragma unroll
        for (int n = 0; n < 2; ++n) {
            int gcol = n0 + wn * 32 + n * 16 + (lane & 15);
#pragma unroll
            for (int j = 0; j < 4; ++j)
                cbase[(size_t)(grow0 + j) * OUT_DIM + gcol] = acc[m][n][j];
        }
    }
}

// Reduce K-split partials, requantize (ACM), add bias.
__global__ __launch_bounds__(256) void finish_kernel(const float* __restrict__ Cp,
                                                     const float* __restrict__ bias,
                                                     float* __restrict__ out) {
    int idx = blockIdx.x * 256 + threadIdx.x;  // quad index, 131072 total
    f32x4 p0 = ((const f32x4*)Cp)[idx];
    f32x4 p1 = ((const f32x4*)Cp)[idx + (B_DIM * OUT_DIM) / 4];
    int o = (idx * 4) & (OUT_DIM - 1);
    f32x4 bv = *(const f32x4*)&bias[o];
    f32x4 r;
#pragma unroll
    for (int j = 0; j < 4; ++j) {
        float s = p0[j] + p1[j];
        float y = s * (1.0f / 16777216.0f);    // 2^-(WFRAC+IFRAC), exact pow2 scale
        float q = rintf(y * 4096.0f);          // half-to-even, matches jnp.round
        q = fminf(fmaxf(q, -32768.0f), 32767.0f);
        r[j] = q * (1.0f / 4096.0f) + bv[j];
    }
    ((f32x4*)out)[idx] = r;
}

extern "C" void kernel_launch(void* const* d_in, const int* in_sizes, int n_in,
                              void* d_out, int out_size, void* d_ws, size_t ws_size,
                              hipStream_t stream) {
    const float* x = (const float*)d_in[0];
    const float* w = (const float*)d_in[1];
    const float* bias = (const float*)d_in[2];
    float* out = (float*)d_out;

    unsigned short* Ap = (unsigned short*)d_ws;                          // 4 MB
    unsigned short* Wp = (unsigned short*)((char*)d_ws + (4u << 20));    // 8 MB
    float* Cp = (float*)((char*)d_ws + (12u << 20));                     // 4 MB

    prep_kernel<<<1536, 256, 0, stream>>>(x, w, Ap, Wp);
    gemm_kernel<<<256, 256, 0, stream>>>(Ap, Wp, Cp);
    finish_kernel<<<512, 256, 0, stream>>>(Cp, bias, out);
}

// Round 2
// 20.723 us; speedup vs baseline: 1.6453x; 1.6453x over previous
//
#include <hip/hip_runtime.h>
#include <stdint.h>

typedef int i32x4 __attribute__((ext_vector_type(4)));
typedef float f32x4 __attribute__((ext_vector_type(4)));
typedef unsigned int u32x2 __attribute__((ext_vector_type(2)));

#define B_DIM 512
#define IN_DIM 1024
#define OUT_DIM 1024
#define KSPLIT 4
#define KB (IN_DIM / KSPLIT)          // 256 original k per block
#define APLANE (B_DIM * IN_DIM)       // 524288 bytes per plane
#define WPLANE (OUT_DIM * IN_DIM)     // 1048576 bytes per plane
#define CPLANE (B_DIM * OUT_DIM)      // 524288 ints per K-split partial

static __device__ __forceinline__ void quant_split(float v, int& hi, int& lo) {
    float t = rintf(v * 4096.0f);              // half-to-even, matches jnp.round
    t = fminf(fmaxf(t, -32768.0f), 32767.0f);
    int q = (int)t;
    lo = ((q + 128) & 255) - 128;              // centered low byte [-128,127]
    hi = (q - lo) >> 8;                        // [-128,127] for this data (|q|<32640)
}

// Quantize x,w to int16, split into hi/lo int8 planes.
// A8: [2][512][1024] i8 (plane-major), W8: [2][1024][1024] i8.
__global__ __launch_bounds__(256) void prep_kernel(const float* __restrict__ x,
                                                   const float* __restrict__ w,
                                                   signed char* __restrict__ A8,
                                                   signed char* __restrict__ W8) {
    const int XT = APLANE / 8;                 // 65536 threads for x
    const int WT = WPLANE / 8;                 // 131072 threads for w
    int tid = blockIdx.x * 256 + threadIdx.x;
    bool isx = tid < XT;
    int g = isx ? tid : tid - XT;
    if (!isx && g >= WT) return;

    const float* src = isx ? x : w;
    signed char* hiP = (isx ? A8 : W8) + (size_t)g * 8;
    signed char* loP = hiP + (isx ? APLANE : WPLANE);

    f32x4 v0 = ((const f32x4*)src)[g * 2];
    f32x4 v1 = ((const f32x4*)src)[g * 2 + 1];

    unsigned char hb[8], lb[8];
#pragma unroll
    for (int j = 0; j < 4; ++j) {
        int hi, lo;
        quant_split(v0[j], hi, lo);
        hb[j] = (unsigned char)hi; lb[j] = (unsigned char)lo;
        quant_split(v1[j], hi, lo);
        hb[4 + j] = (unsigned char)hi; lb[4 + j] = (unsigned char)lo;
    }
    *(u32x2*)hiP = *(const u32x2*)hb;
    *(u32x2*)loP = *(const u32x2*)lb;
}

// Exact int8 NT GEMM with bit-weighted recombination.
// C[b,o] = sum_k xq[b,k]*wq[o,k] = 65536*hh + 256*(hl+lh) + ll.
// 64x64 tile, K-split 4 -> 512 blocks (2/CU), 4 waves of 32x32.
// Whole per-block operand set staged once: LDS [2][64][256] i8 per matrix.
// 16B slots XOR-swizzled (phys = s ^ (row&7)) via pre-swizzled global source.
__global__ __launch_bounds__(256, 2) void gemm_kernel(const signed char* __restrict__ A8,
                                                      const signed char* __restrict__ W8,
                                                      int* __restrict__ Cp) {
    __shared__ signed char sA[2 * 64 * 256];   // 32 KiB
    __shared__ signed char sB[2 * 64 * 256];   // 32 KiB

    int bid = blockIdx.x;
    bid = (bid & 7) * 64 + (bid >> 3);         // XCD chunk swizzle (512 % 8 == 0)
    int nblk = bid & 15;
    int mblk = (bid >> 4) & 7;
    int ks = bid >> 7;

    int t = threadIdx.x;
    int lane = t & 63;
    int wv = t >> 6;
    int wm = wv >> 1, wn = wv & 1;
    int m0 = mblk * 64, n0 = nblk * 64, k0 = ks * KB;

#pragma unroll
    for (int i = 0; i < 8; ++i) {
        int idx = i * 256 + t;                 // 16B slot: [p][row][s]
        int p = idx >> 10;
        int row = (idx >> 4) & 63;
        int s = idx & 15;
        int ssw = s ^ (row & 7);
        const signed char* ga = A8 + (size_t)p * APLANE + (size_t)(m0 + row) * IN_DIM + k0 + ssw * 16;
        __builtin_amdgcn_global_load_lds(
            (const __attribute__((address_space(1))) void*)ga,
            (__attribute__((address_space(3))) void*)&sA[idx * 16], 16, 0, 0);
        const signed char* gb = W8 + (size_t)p * WPLANE + (size_t)(n0 + row) * IN_DIM + k0 + ssw * 16;
        __builtin_amdgcn_global_load_lds(
            (const __attribute__((address_space(1))) void*)gb,
            (__attribute__((address_space(3))) void*)&sB[idx * 16], 16, 0, 0);
    }
    __syncthreads();

    i32x4 hh[2][2] = {}, mid[2][2] = {}, ll[2][2] = {};
#pragma unroll
    for (int c = 0; c < 4; ++c) {
        i32x4 a[2][2], b[2][2];
#pragma unroll
        for (int m = 0; m < 2; ++m) {
            int row = wm * 32 + m * 16 + (lane & 15);
            int phys = (c * 4 + (lane >> 4)) ^ (row & 7);
#pragma unroll
            for (int p = 0; p < 2; ++p)
                a[m][p] = *(const i32x4*)&sA[p * 16384 + row * 256 + phys * 16];
        }
#pragma unroll
        for (int n = 0; n < 2; ++n) {
            int row = wn * 32 + n * 16 + (lane & 15);
            int phys = (c * 4 + (lane >> 4)) ^ (row & 7);
#pragma unroll
            for (int p = 0; p < 2; ++p)
                b[n][p] = *(const i32x4*)&sB[p * 16384 + row * 256 + phys * 16];
        }
#pragma unroll
        for (int m = 0; m < 2; ++m)
#pragma unroll
            for (int n = 0; n < 2; ++n) {
                hh[m][n]  = __builtin_amdgcn_mfma_i32_16x16x64_i8(a[m][0], b[n][0], hh[m][n], 0, 0, 0);
                mid[m][n] = __builtin_amdgcn_mfma_i32_16x16x64_i8(a[m][0], b[n][1], mid[m][n], 0, 0, 0);
                mid[m][n] = __builtin_amdgcn_mfma_i32_16x16x64_i8(a[m][1], b[n][0], mid[m][n], 0, 0, 0);
                ll[m][n]  = __builtin_amdgcn_mfma_i32_16x16x64_i8(a[m][1], b[n][1], ll[m][n], 0, 0, 0);
            }
    }

    // C/D layout: col = lane&15, row = (lane>>4)*4 + reg (dtype-independent)
    int* cbase = Cp + (size_t)ks * CPLANE;
#pragma unroll
    for (int m = 0; m < 2; ++m) {
        int grow0 = m0 + wm * 32 + m * 16 + ((lane >> 4) << 2);
#pragma unroll
        for (int n = 0; n < 2; ++n) {
            int gcol = n0 + wn * 32 + n * 16 + (lane & 15);
#pragma unroll
            for (int j = 0; j < 4; ++j) {
                int ssum = hh[m][n][j] * 65536 + mid[m][n][j] * 256 + ll[m][n][j];
                cbase[(size_t)(grow0 + j) * OUT_DIM + gcol] = ssum;
            }
        }
    }
}

// Sum 4 exact int partials, requantize (exact double rint), add bias.
__global__ __launch_bounds__(256) void finish_kernel(const int* __restrict__ Cp,
                                                     const float* __restrict__ bias,
                                                     float* __restrict__ out) {
    int idx = blockIdx.x * 256 + threadIdx.x;  // quad index, 131072 total
    i32x4 s0 = ((const i32x4*)(Cp + 0 * CPLANE))[idx];
    i32x4 s1 = ((const i32x4*)(Cp + 1 * CPLANE))[idx];
    i32x4 s2 = ((const i32x4*)(Cp + 2 * CPLANE))[idx];
    i32x4 s3 = ((const i32x4*)(Cp + 3 * CPLANE))[idx];
    int o = (idx * 4) & (OUT_DIM - 1);
    f32x4 bv = *(const f32x4*)&bias[o];
    f32x4 r;
#pragma unroll
    for (int j = 0; j < 4; ++j) {
        int s = s0[j] + s1[j] + s2[j] + s3[j];          // exact total acc
        double q = rint((double)s * 0x1p-12);           // round(acc*2^-12), exact
        q = q < -32768.0 ? -32768.0 : (q > 32767.0 ? 32767.0 : q);
        r[j] = (float)(q * 0x1p-12) + bv[j];
    }
    ((f32x4*)out)[idx] = r;
}

extern "C" void kernel_launch(void* const* d_in, const int* in_sizes, int n_in,
                              void* d_out, int out_size, void* d_ws, size_t ws_size,
                              hipStream_t stream) {
    const float* x = (const float*)d_in[0];
    const float* w = (const float*)d_in[1];
    const float* bias = (const float*)d_in[2];
    float* out = (float*)d_out;

    signed char* A8 = (signed char*)d_ws;                           // 1 MB
    signed char* W8 = (signed char*)d_ws + (1u << 20);              // 2 MB
    int* Cp = (int*)((char*)d_ws + (3u << 20));                     // 8 MB

    prep_kernel<<<768, 256, 0, stream>>>(x, w, A8, W8);
    gemm_kernel<<<512, 256, 0, stream>>>(A8, W8, Cp);
    finish_kernel<<<512, 256, 0, stream>>>(Cp, bias, out);
}

// Round 3
// 16.561 us; speedup vs baseline: 2.0588x; 1.2513x over previous
//
#include <hip/hip_runtime.h>
#include <stdint.h>

typedef int i32x4 __attribute__((ext_vector_type(4)));
typedef float f32x4 __attribute__((ext_vector_type(4)));
typedef unsigned int u32x2 __attribute__((ext_vector_type(2)));

#define B_DIM 512
#define IN_DIM 1024
#define OUT_DIM 1024
#define APLANE (B_DIM * IN_DIM)       // 524288 bytes per i8 plane
#define WPLANE (OUT_DIM * IN_DIM)     // 1048576 bytes per i8 plane
#define KC 256                         // K-chunk bytes per stage

static __device__ __forceinline__ void quant_split(float v, int& hi, int& lo) {
    float t = rintf(v * 4096.0f);              // half-to-even, matches jnp.round
    t = fminf(fmaxf(t, -32768.0f), 32767.0f);
    int q = (int)t;
    lo = ((q + 128) & 255) - 128;              // centered low byte [-128,127]
    hi = (q - lo) >> 8;                        // [-128,127] for this data (|q|<32640)
}

// Quantize x,w to int16, split into hi/lo int8 planes.
// A8: [2][512][1024] i8 (plane-major), W8: [2][1024][1024] i8.
__global__ __launch_bounds__(256) void prep_kernel(const float* __restrict__ x,
                                                   const float* __restrict__ w,
                                                   signed char* __restrict__ A8,
                                                   signed char* __restrict__ W8) {
    const int XT = APLANE / 8;                 // 65536 threads for x
    const int WT = WPLANE / 8;                 // 131072 threads for w
    int tid = blockIdx.x * 256 + threadIdx.x;
    bool isx = tid < XT;
    int g = isx ? tid : tid - XT;
    if (!isx && g >= WT) return;

    const float* src = isx ? x : w;
    signed char* hiP = (isx ? A8 : W8) + (size_t)g * 8;
    signed char* loP = hiP + (isx ? APLANE : WPLANE);

    f32x4 v0 = ((const f32x4*)src)[g * 2];
    f32x4 v1 = ((const f32x4*)src)[g * 2 + 1];

    unsigned char hb[8], lb[8];
#pragma unroll
    for (int j = 0; j < 4; ++j) {
        int hi, lo;
        quant_split(v0[j], hi, lo);
        hb[j] = (unsigned char)hi; lb[j] = (unsigned char)lo;
        quant_split(v1[j], hi, lo);
        hb[4 + j] = (unsigned char)hi; lb[4 + j] = (unsigned char)lo;
    }
    *(u32x2*)hiP = *(const u32x2*)hb;
    *(u32x2*)loP = *(const u32x2*)lb;
}

// Fused exact int8 NT GEMM + requantize + bias.
// C[b,o] = 65536*hh + 256*(hl+lh) + ll over full K=1024 per block.
// 32x32 tile -> 16x32 = 512 blocks (2/CU). 4 waves, one 16x16 quadrant each.
// K staged in 4 double-buffered chunks of 256 bytes/row/plane.
// 16B slots XOR-swizzled (phys = s ^ (row&7)) via pre-swizzled global source.
__global__ __launch_bounds__(256, 2) void gemm_fused_kernel(const signed char* __restrict__ A8,
                                                            const signed char* __restrict__ W8,
                                                            const float* __restrict__ bias,
                                                            float* __restrict__ out) {
    // per buffer per matrix: [2 planes][32 rows][256 bytes] = 16 KiB
    __shared__ signed char sA[2][16384];
    __shared__ signed char sB[2][16384];

    int bid = blockIdx.x;
    bid = (bid & 7) * 64 + (bid >> 3);         // XCD chunk swizzle (512 % 8 == 0)
    int nblk = bid & 31;
    int mblk = bid >> 5;
    int m0 = mblk * 32, n0 = nblk * 32;

    int t = threadIdx.x;
    int lane = t & 63;
    int wv = t >> 6;
    int wm = wv >> 1, wn = wv & 1;

    // --- staging lambda: chunk c (k-bytes [c*256, c*256+256)) into buf ---
    auto stage = [&](int c, int buf) {
#pragma unroll
        for (int i = 0; i < 4; ++i) {
            int idx = i * 256 + t;             // 16B slot: [plane][row][s]
            int p = idx >> 9;
            int row = (idx >> 4) & 31;
            int s = idx & 15;
            int ssw = s ^ (row & 7);
            const signed char* ga = A8 + (size_t)p * APLANE + (size_t)(m0 + row) * IN_DIM + c * KC + ssw * 16;
            __builtin_amdgcn_global_load_lds(
                (const __attribute__((address_space(1))) void*)ga,
                (__attribute__((address_space(3))) void*)&sA[buf][idx * 16], 16, 0, 0);
            const signed char* gb = W8 + (size_t)p * WPLANE + (size_t)(n0 + row) * IN_DIM + c * KC + ssw * 16;
            __builtin_amdgcn_global_load_lds(
                (const __attribute__((address_space(1))) void*)gb,
                (__attribute__((address_space(3))) void*)&sB[buf][idx * 16], 16, 0, 0);
        }
    };

    i32x4 hh = {}, mid = {}, ll = {};
    int arow = wm * 16 + (lane & 15);          // LDS row for A fragment
    int brow = wn * 16 + (lane & 15);          // LDS row for B fragment

    stage(0, 0);
    __syncthreads();

    int buf = 0;
    for (int c = 0; c < 4; ++c) {
        if (c < 3) stage(c + 1, buf ^ 1);
#pragma unroll
        for (int k4 = 0; k4 < 4; ++k4) {
            int aphys = (k4 * 4 + (lane >> 4)) ^ (arow & 7);
            int bphys = (k4 * 4 + (lane >> 4)) ^ (brow & 7);
            i32x4 a0 = *(const i32x4*)&sA[buf][arow * 256 + aphys * 16];
            i32x4 a1 = *(const i32x4*)&sA[buf][8192 + arow * 256 + aphys * 16];
            i32x4 b0 = *(const i32x4*)&sB[buf][brow * 256 + bphys * 16];
            i32x4 b1 = *(const i32x4*)&sB[buf][8192 + brow * 256 + bphys * 16];
            hh  = __builtin_amdgcn_mfma_i32_16x16x64_i8(a0, b0, hh, 0, 0, 0);
            mid = __builtin_amdgcn_mfma_i32_16x16x64_i8(a0, b1, mid, 0, 0, 0);
            mid = __builtin_amdgcn_mfma_i32_16x16x64_i8(a1, b0, mid, 0, 0, 0);
            ll  = __builtin_amdgcn_mfma_i32_16x16x64_i8(a1, b1, ll, 0, 0, 0);
        }
        __syncthreads();                        // drains vmcnt(0) too (next chunk ready)
        buf ^= 1;
    }

    // Epilogue: exact combine, requantize, bias. C/D: col=lane&15, row=(lane>>4)*4+j
    int gcol = n0 + wn * 16 + (lane & 15);
    int grow0 = m0 + wm * 16 + ((lane >> 4) << 2);
    float bv = bias[gcol];
#pragma unroll
    for (int j = 0; j < 4; ++j) {
        int s = hh[j] * 65536 + mid[j] * 256 + ll[j];   // exact int32 acc
        double q = rint((double)s * 0x1p-12);           // round(acc*2^-12), exact
        q = q < -32768.0 ? -32768.0 : (q > 32767.0 ? 32767.0 : q);
        out[(size_t)(grow0 + j) * OUT_DIM + gcol] = (float)(q * 0x1p-12) + bv;
    }
}

extern "C" void kernel_launch(void* const* d_in, const int* in_sizes, int n_in,
                              void* d_out, int out_size, void* d_ws, size_t ws_size,
                              hipStream_t stream) {
    const float* x = (const float*)d_in[0];
    const float* w = (const float*)d_in[1];
    const float* bias = (const float*)d_in[2];
    float* out = (float*)d_out;

    signed char* A8 = (signed char*)d_ws;                // 1 MB
    signed char* W8 = (signed char*)d_ws + (1u << 20);   // 2 MB

    prep_kernel<<<768, 256, 0, stream>>>(x, w, A8, W8);
    gemm_fused_kernel<<<512, 256, 0, stream>>>(A8, W8, bias, out);
}